// Round 6
// baseline (1548.461 us; speedup 1.0000x reference)
//
#include <hip/hip_runtime.h>
#include <hip/hip_bf16.h>
#include <math.h>

#define BATCHN   128
#define SEQN     64
#define WDIM     300
#define WDIMP    320            // padded K for embed GEMM
#define MDIM     512
#define HIDN     256
#define NGATES   1280           // 5*HIDN
#define MLPD     1024
#define NCLS     3
#define NGRP     16             // batch groups of 8
#define NSLICE   16             // hid-col slices of 16

typedef __bf16 bf16x8 __attribute__((ext_vector_type(8)));
typedef float  f32x4  __attribute__((ext_vector_type(4)));

__device__ __forceinline__ float sigmoidf_(float x) {
    return 1.0f / (1.0f + __expf(-x));
}
__device__ __forceinline__ float tanhf_(float x) {
    x = fminf(fmaxf(x, -15.0f), 15.0f);
    float e = __expf(2.0f * x);
    return (e - 1.0f) / (e + 1.0f);
}

// ---------------------------------------------------------------------------
// Fused weight pack: all f32 weights -> bf16 MFMA fragment order Bp[kc][n][8]
// ---------------------------------------------------------------------------
#define PK_B0   81920           // 64*1280   [Wl;Wr]
#define PK_B1   20480           // 40*512    Wp (300->320)
#define PK_B2   65536           // 64*1024   W0
#define PK_B3  131072           // 128*1024  W1
__global__ __launch_bounds__(256)
void pack_all_kernel(const float* __restrict__ Wl, const float* __restrict__ Wr,
                     const float* __restrict__ Wp, const float* __restrict__ W0,
                     const float* __restrict__ W1,
                     __hip_bfloat16* __restrict__ Bp,
                     __hip_bfloat16* __restrict__ BpWp,
                     __hip_bfloat16* __restrict__ BpW0,
                     __hip_bfloat16* __restrict__ BpW1)
{
    int gid = blockIdx.x * 256 + threadIdx.x;
    __hip_bfloat16 tmp[8];
    if (gid < PK_B0) {
        int kc = gid / NGATES, n = gid - kc * NGATES;
#pragma unroll
        for (int j = 0; j < 8; ++j) {
            int k = kc * 8 + j;
            float v = (k < HIDN) ? Wl[k * NGATES + n] : Wr[(k - HIDN) * NGATES + n];
            tmp[j] = __float2bfloat16(v);
        }
        *(bf16x8*)(Bp + (size_t)gid * 8) = *(const bf16x8*)tmp;
    } else if (gid < PK_B0 + PK_B1) {
        int u = gid - PK_B0;
        int kc = u >> 9, n = u & 511;
#pragma unroll
        for (int j = 0; j < 8; ++j) {
            int k = kc * 8 + j;
            tmp[j] = __float2bfloat16((k < WDIM) ? Wp[(size_t)k * MDIM + n] : 0.f);
        }
        *(bf16x8*)(BpWp + (size_t)u * 8) = *(const bf16x8*)tmp;
    } else if (gid < PK_B0 + PK_B1 + PK_B2) {
        int u = gid - PK_B0 - PK_B1;
        int kc = u >> 10, n = u & 1023;
#pragma unroll
        for (int j = 0; j < 8; ++j)
            tmp[j] = __float2bfloat16(W0[(size_t)(kc * 8 + j) * MLPD + n]);
        *(bf16x8*)(BpW0 + (size_t)u * 8) = *(const bf16x8*)tmp;
    } else if (gid < PK_B0 + PK_B1 + PK_B2 + PK_B3) {
        int u = gid - PK_B0 - PK_B1 - PK_B2;
        int kc = u >> 10, n = u & 1023;
#pragma unroll
        for (int j = 0; j < 8; ++j)
            tmp[j] = __float2bfloat16(W1[(size_t)(kc * 8 + j) * MLPD + n]);
        *(bf16x8*)(BpW1 + (size_t)u * 8) = *(const bf16x8*)tmp;
    }
}

// ---------------------------------------------------------------------------
// State layout (group-major): row(b, s) = (b>>3)*512 + s*8 + (b&7); [row][256]
// h bf16, c f32. Group g owns rows g*512 .. g*512+511 (64 pos x 8 batch).
// ---------------------------------------------------------------------------
__device__ __forceinline__ size_t grow(int b, int s) {
    return ((size_t)(b >> 3) << 9) + ((size_t)s << 3) + (b & 7);
}

// ---------------------------------------------------------------------------
// K1: embed gather + projection via MFMA (writes group layout).
// ---------------------------------------------------------------------------
__global__ __launch_bounds__(256)
void embed_mfma_kernel(const int* __restrict__ sent,
                       const float* __restrict__ emb,
                       const __hip_bfloat16* __restrict__ BpWp,  // [40][512][8]
                       const float* __restrict__ bp,
                       __hip_bfloat16* __restrict__ hout,
                       float* __restrict__ cout)
{
    __shared__ __align__(16) __hip_bfloat16 Ae[WDIMP / 8][32][8];   // 20 KB
    const int tid  = threadIdx.x;
    const int tok0 = blockIdx.x * 32;

#pragma unroll
    for (int i = 0; i < 20; ++i) {
        int idx = i * 256 + tid;              // over 32 rows x 160 k-pairs
        int r  = idx / 160;
        int kp = idx - r * 160;
        int k  = kp * 2;
        float2 v = make_float2(0.f, 0.f);
        if (k < WDIM)
            v = *(const float2*)&emb[(size_t)sent[tok0 + r] * WDIM + k];
        __hip_bfloat162 h2;
        h2.x = __float2bfloat16(v.x);
        h2.y = __float2bfloat16(v.y);
        *(__hip_bfloat162*)&Ae[k >> 3][r][k & 7] = h2;
    }
    __syncthreads();

    const int lane = tid & 63;
    const int wid  = tid >> 6;
    const int l15  = lane & 15;
    const int kgrp = lane >> 4;
    const int col0 = blockIdx.y * 256 + wid * 64;

    f32x4 acc[2][4];
#pragma unroll
    for (int rf = 0; rf < 2; ++rf)
#pragma unroll
        for (int cf = 0; cf < 4; ++cf)
            acc[rf][cf] = (f32x4){0.f, 0.f, 0.f, 0.f};

    const bf16x8* BpV = (const bf16x8*)BpWp;
#pragma unroll
    for (int ks = 0; ks < WDIMP / 32; ++ks) {
        const int kc = ks * 4 + kgrp;
        bf16x8 a0 = *(const bf16x8*)&Ae[kc][l15][0];
        bf16x8 a1 = *(const bf16x8*)&Ae[kc][16 + l15][0];
        const bf16x8* Brow = BpV + (size_t)kc * MDIM + col0 + l15;
#pragma unroll
        for (int cf = 0; cf < 4; ++cf) {
            bf16x8 bfr = Brow[cf * 16];
            acc[0][cf] = __builtin_amdgcn_mfma_f32_16x16x32_bf16(a0, bfr, acc[0][cf], 0, 0, 0);
            acc[1][cf] = __builtin_amdgcn_mfma_f32_16x16x32_bf16(a1, bfr, acc[1][cf], 0, 0, 0);
        }
    }

#pragma unroll
    for (int rf = 0; rf < 2; ++rf)
#pragma unroll
        for (int reg = 0; reg < 4; ++reg) {
            int row = tok0 + rf * 16 + kgrp * 4 + reg;   // token = b*64+s
            int b = row >> 6, s = row & 63;
            size_t sr = grow(b, s);
#pragma unroll
            for (int cf = 0; cf < 4; ++cf) {
                int col = col0 + cf * 16 + l15;
                float v = acc[rf][cf][reg] + bp[col];
                if (col < HIDN)
                    hout[sr * HIDN + col] = __float2bfloat16(v);
                else
                    cout[sr * HIDN + (col - HIDN)] = v;
            }
        }
}

// ---------------------------------------------------------------------------
// K2: PERSISTENT tree kernel — all 63 levels, cooperative launch.
// 256 blocks x 512 threads (8 waves). Block (x = bx&7 -> XCD, y = bx>>3):
// grp = x*2 + (y>>4)  (16 blocks of a group share an XCD -> state L2-local),
// slice = y&15 (16 hid cols x 5 gates -> 80 KB B-slice staged ONCE in LDS).
// Per level: frag f (16 state rows) -> wave f&7; per wave <=4 frags.
// Group barrier (16 blocks) between levels via agent-scope atomics.
// ---------------------------------------------------------------------------
__global__ __launch_bounds__(512, 2)
void tree_persistent(__hip_bfloat16* __restrict__ h0, float* __restrict__ c0,
                     __hip_bfloat16* __restrict__ h1, float* __restrict__ c1,
                     const __hip_bfloat16* __restrict__ Bp,
                     const float* __restrict__ bc,
                     int* __restrict__ bar)
{
    __shared__ __align__(16) __hip_bfloat16 Bs[64][5][16][8];   // 80 KB

    const int tid  = threadIdx.x;
    const int lane = tid & 63;
    const int wid  = tid >> 6;          // 0..7
    const int l15  = lane & 15;
    const int kgrp = lane >> 4;

    const int bx    = blockIdx.x;
    const int grp   = (bx & 7) * 2 + ((bx >> 3) >> 4);
    const int slice = (bx >> 3) & 15;

    // ---- stage B-slice once: 10 x (512 thr x 16 B) = 80 KB
#pragma unroll
    for (int i = 0; i < 10; ++i) {
        int flat = i * 512 + tid;              // (kc*5+g)*16 + j
        int kc  = flat / 80;
        int rem = flat - kc * 80;
        int g   = rem >> 4;
        int j   = rem & 15;
        const __hip_bfloat16* src =
            Bp + ((size_t)kc * NGATES + g * HIDN + slice * 16 + j) * 8;
        __builtin_amdgcn_global_load_lds(
            (const __attribute__((address_space(1))) unsigned int*)src,
            (__attribute__((address_space(3))) unsigned int*)
                ((char*)&Bs[0][0][0][0] + (size_t)flat * 16),
            16, 0, 0);
    }

    const int col = slice * 16 + l15;
    float bias[5];
#pragma unroll
    for (int g = 0; g < 5; ++g) bias[g] = bc[g * HIDN + col];

    const size_t goff = (size_t)grp * 512 * HIDN;
    __hip_bfloat16* hA = h0 + goff;  float* cA = c0 + goff;
    __hip_bfloat16* hB = h1 + goff;  float* cB = c1 + goff;

    __syncthreads();    // waits vmcnt(0) -> B staged

#pragma unroll 1
    for (int t = 1; t < SEQN; ++t) {
        const int R = SEQN - t;
        const __hip_bfloat16* hin = (t & 1) ? hA : hB;
        const float*          cin = (t & 1) ? cA : cB;
        __hip_bfloat16*      hout = (t & 1) ? hB : hA;
        float*               cout_ = (t & 1) ? cB : cA;

        const int nfrag = (8 * R + 15) >> 4;
        const int nf = (nfrag - wid + 7) >> 3;   // my frag count (0..4)

        if (nf > 0) {
            f32x4 acc[4][5];
#pragma unroll
            for (int i = 0; i < 4; ++i)
#pragma unroll
                for (int g = 0; g < 5; ++g)
                    acc[i][g] = (f32x4){0.f, 0.f, 0.f, 0.f};

            const __hip_bfloat16* aptr[4];
#pragma unroll
            for (int i = 0; i < 4; ++i)
                aptr[i] = hin + (size_t)((wid + 8 * i) * 16 + l15) * HIDN;

#pragma unroll 1
            for (int ks = 0; ks < 16; ++ks) {
                const int kg   = ks * 32 + kgrp * 8;
                const int half = kg >> 8;          // 0=left, 1=right(+8 rows)
                const int kl   = kg & 255;
                bf16x8 bb[5];
#pragma unroll
                for (int g = 0; g < 5; ++g)
                    bb[g] = *(const bf16x8*)&Bs[ks * 4 + kgrp][g][l15][0];
#pragma unroll
                for (int i = 0; i < 4; ++i) {
                    if (i < nf) {
                        bf16x8 a = *(const bf16x8*)(aptr[i] + half * (8 * HIDN) + kl);
#pragma unroll
                        for (int g = 0; g < 5; ++g)
                            acc[i][g] = __builtin_amdgcn_mfma_f32_16x16x32_bf16(a, bb[g], acc[i][g], 0, 0, 0);
                    }
                }
            }

            // epilogue: C row = (lane>>4)*4+reg, C col = l15
#pragma unroll
            for (int i = 0; i < 4; ++i) {
                if (i < nf) {
                    const int f = wid + 8 * i;
#pragma unroll
                    for (int reg = 0; reg < 4; ++reg) {
                        int r = f * 16 + kgrp * 4 + reg;
                        int p = r >> 3;
                        if (p < R) {
                            float clv = cin[(size_t)r * HIDN + col];
                            float crv = cin[(size_t)(r + 8) * HIDN + col];
                            float i_ = acc[i][0][reg] + bias[0];
                            float fl = acc[i][1][reg] + bias[1];
                            float fr = acc[i][2][reg] + bias[2];
                            float o_ = acc[i][3][reg] + bias[3];
                            float g_ = acc[i][4][reg] + bias[4];
                            float c  = clv * sigmoidf_(fl) + crv * sigmoidf_(fr)
                                     + sigmoidf_(i_) * tanhf_(g_);
                            hout[(size_t)r * HIDN + col] = __float2bfloat16(sigmoidf_(o_) * tanhf_(c));
                            cout_[(size_t)r * HIDN + col] = c;
                        }
                    }
                }
            }
        }

        // ---- group barrier (16 slice-blocks of this group)
        __syncthreads();   // drains all waves' stores (vmcnt 0) before arrive
        if (tid == 0) {
            int* cnt = bar + (t - 1) * NGRP + grp;
            __hip_atomic_fetch_add(cnt, 1, __ATOMIC_ACQ_REL, __HIP_MEMORY_SCOPE_AGENT);
            while (__hip_atomic_load(cnt, __ATOMIC_ACQUIRE, __HIP_MEMORY_SCOPE_AGENT) < NSLICE)
                __builtin_amdgcn_s_sleep(2);
        }
        __syncthreads();
    }
}

// ---------------------------------------------------------------------------
// Assemble MLP input (bf16): x[b,:] = [ h(root_b) | bf16(c(root_b)) ]
// ---------------------------------------------------------------------------
__global__ __launch_bounds__(256)
void gather_root_kernel(const __hip_bfloat16* __restrict__ h,
                        const float* __restrict__ c,
                        __hip_bfloat16* __restrict__ x)
{
    int idx = blockIdx.x * 256 + threadIdx.x;     // 128*512
    int b   = idx >> 9;
    int col = idx & 511;
    size_t sr = grow(b, 0);                       // root = pos 0
    __hip_bfloat16 v = (col < HIDN) ? h[sr * HIDN + col]
                                    : __float2bfloat16(c[sr * HIDN + (col - HIDN)]);
    x[idx] = v;
}

// ---------------------------------------------------------------------------
// K3: MFMA dense layer  out[128, N] = relu(A[128, K] @ W + bias), bf16 I/O.
// ---------------------------------------------------------------------------
template <int K, int N, bool RELU>
__global__ __launch_bounds__(256)
void mlp_mfma_kernel(const __hip_bfloat16* __restrict__ A,
                     const __hip_bfloat16* __restrict__ Bp,
                     const float* __restrict__ bias,
                     __hip_bfloat16* __restrict__ out)
{
    const int lane = threadIdx.x & 63;
    const int wid  = threadIdx.x >> 6;
    const int l15  = lane & 15;
    const int kgrp = lane >> 4;
    const int m0   = blockIdx.x * 32;
    const int col0 = blockIdx.y * 64 + wid * 16;

    f32x4 acc[2];
    acc[0] = (f32x4){0.f, 0.f, 0.f, 0.f};
    acc[1] = (f32x4){0.f, 0.f, 0.f, 0.f};

    const bf16x8* BpV = (const bf16x8*)Bp;
#pragma unroll 4
    for (int ks = 0; ks < K / 32; ++ks) {
        const int kl = ks * 32 + kgrp * 8;
        bf16x8 a0 = *(const bf16x8*)(A + (size_t)(m0 + l15)      * K + kl);
        bf16x8 a1 = *(const bf16x8*)(A + (size_t)(m0 + 16 + l15) * K + kl);
        bf16x8 bfr = BpV[(size_t)(ks * 4 + kgrp) * N + col0 + l15];
        acc[0] = __builtin_amdgcn_mfma_f32_16x16x32_bf16(a0, bfr, acc[0], 0, 0, 0);
        acc[1] = __builtin_amdgcn_mfma_f32_16x16x32_bf16(a1, bfr, acc[1], 0, 0, 0);
    }

    const int col = col0 + l15;
    const float bv = bias[col];
#pragma unroll
    for (int rf = 0; rf < 2; ++rf)
#pragma unroll
        for (int reg = 0; reg < 4; ++reg) {
            int m = m0 + rf * 16 + kgrp * 4 + reg;
            float v = acc[rf][reg] + bv;
            if (RELU) v = fmaxf(v, 0.f);
            out[(size_t)m * N + col] = __float2bfloat16(v);
        }
}

// ---------------------------------------------------------------------------
// K4: final layer (N=3): one wave per row, lane-parallel K, shuffle reduce.
// ---------------------------------------------------------------------------
__global__ __launch_bounds__(256)
void mlp_out_kernel(const __hip_bfloat16* __restrict__ A,
                    const float* __restrict__ Wo,
                    const float* __restrict__ bo,
                    float* __restrict__ out)
{
    const int lane = threadIdx.x & 63;
    const int row  = blockIdx.x * 4 + (threadIdx.x >> 6);
    float a0 = 0.f, a1 = 0.f, a2 = 0.f;
    for (int k = lane; k < MLPD; k += 64) {
        float x = __bfloat162float(A[(size_t)row * MLPD + k]);
        a0 += x * Wo[k * NCLS + 0];
        a1 += x * Wo[k * NCLS + 1];
        a2 += x * Wo[k * NCLS + 2];
    }
#pragma unroll
    for (int off = 32; off >= 1; off >>= 1) {
        a0 += __shfl_down(a0, off, 64);
        a1 += __shfl_down(a1, off, 64);
        a2 += __shfl_down(a2, off, 64);
    }
    if (lane == 0) {
        out[row * NCLS + 0] = a0 + bo[0];
        out[row * NCLS + 1] = a1 + bo[1];
        out[row * NCLS + 2] = a2 + bo[2];
    }
}

// ---------------------------------------------------------------------------
extern "C" void kernel_launch(void* const* d_in, const int* in_sizes, int n_in,
                              void* d_out, int out_size, void* d_ws, size_t ws_size,
                              hipStream_t stream)
{
    const int*   sent = (const int*)d_in[0];
    const float* emb  = (const float*)d_in[2];
    const float* Wp   = (const float*)d_in[3];
    const float* bp   = (const float*)d_in[4];
    const float* Wl   = (const float*)d_in[5];
    const float* Wr   = (const float*)d_in[6];
    const float* bc   = (const float*)d_in[7];
    const float* W0   = (const float*)d_in[8];
    const float* b0   = (const float*)d_in[9];
    const float* W1   = (const float*)d_in[10];
    const float* b1   = (const float*)d_in[11];
    const float* Wo   = (const float*)d_in[12];
    const float* bo   = (const float*)d_in[13];
    float* outp = (float*)d_out;

    const size_t NSTATE = (size_t)BATCHN * SEQN * HIDN;

    char* p = (char*)d_ws;
    __hip_bfloat16* h0   = (__hip_bfloat16*)p;  p += NSTATE * 2;
    __hip_bfloat16* h1   = (__hip_bfloat16*)p;  p += NSTATE * 2;
    float* c0            = (float*)p;           p += NSTATE * 4;
    float* c1            = (float*)p;           p += NSTATE * 4;
    __hip_bfloat16* Bp   = (__hip_bfloat16*)p;  p += (size_t)512 * NGATES * 2;
    __hip_bfloat16* BpWp = (__hip_bfloat16*)p;  p += (size_t)WDIMP * MDIM * 2;
    __hip_bfloat16* BpW0 = (__hip_bfloat16*)p;  p += (size_t)MDIM * MLPD * 2;
    __hip_bfloat16* BpW1 = (__hip_bfloat16*)p;  p += (size_t)MLPD * MLPD * 2;
    __hip_bfloat16* xr   = (__hip_bfloat16*)p;  p += (size_t)BATCHN * MDIM * 2;
    __hip_bfloat16* x0   = (__hip_bfloat16*)p;  p += (size_t)BATCHN * MLPD * 2;
    __hip_bfloat16* x1   = (__hip_bfloat16*)p;  p += (size_t)BATCHN * MLPD * 2;
    int* bar             = (int*)p;             p += (size_t)(SEQN - 1) * NGRP * 4;

    // 0) zero barrier counters + pack weights
    hipMemsetAsync(bar, 0, (size_t)(SEQN - 1) * NGRP * 4, stream);
    const int PK_TOT = PK_B0 + PK_B1 + PK_B2 + PK_B3;
    pack_all_kernel<<<(PK_TOT + 255) / 256, 256, 0, stream>>>(
        Wl, Wr, Wp, W0, W1, Bp, BpWp, BpW0, BpW1);

    // 1) embedding gather + projection (MFMA, group-layout output)
    embed_mfma_kernel<<<dim3(BATCHN * SEQN / 32, 2), 256, 0, stream>>>(
        sent, emb, BpWp, bp, h0, c0);

    // 2) all 63 tree-LSTM levels in ONE cooperative persistent kernel
    {
        __hip_bfloat16* a0_ = h0; float* a1_ = c0;
        __hip_bfloat16* a2_ = h1; float* a3_ = c1;
        const __hip_bfloat16* a4_ = Bp;
        const float* a5_ = bc;
        int* a6_ = bar;
        void* kargs[] = {&a0_, &a1_, &a2_, &a3_, &a4_, &a5_, &a6_};
        hipLaunchCooperativeKernel((const void*)tree_persistent,
                                   dim3(256), dim3(512), kargs, 0, stream);
    }

    // 3) MLP head on root states (final state in h1/c1 after 63 levels)
    gather_root_kernel<<<(BATCHN * MDIM) / 256, 256, 0, stream>>>(h1, c1, xr);
    mlp_mfma_kernel<MDIM, MLPD, true><<<dim3(4, 16), 256, 0, stream>>>(xr, BpW0, b0, x0);
    mlp_mfma_kernel<MLPD, MLPD, true><<<dim3(4, 16), 256, 0, stream>>>(x0, BpW1, b1, x1);
    mlp_out_kernel<<<32, 256, 0, stream>>>(x1, Wo, bo, outp);
}

// Round 7
// 1070.600 us; speedup vs baseline: 1.4463x; 1.4463x over previous
//
#include <hip/hip_runtime.h>
#include <hip/hip_bf16.h>
#include <math.h>

#define BATCHN   128
#define SEQN     64
#define WDIM     300
#define WDIMP    320            // padded K for embed GEMM
#define MDIM     512
#define HIDN     256
#define NGATES   1280           // 5*HIDN
#define MLPD     1024
#define NCLS     3
#define NGRP     16             // batch groups of 8
#define NSLICE   16             // hid-col slices of 16
#define NLVL     (SEQN - 1)

// barrier-word layout in d_ws
#define BAR_G0   0              // startup grid barrier #1
#define BAR_G1   1              // startup grid barrier #2
#define BAR_XCD  2              // [NGRP] leader XCD per group
#define BAR_BAD  18             // global mismatch counter
#define BAR_LVL  64             // [NLVL][NGRP] per-level group barriers
#define BAR_TOT  (BAR_LVL + NLVL * NGRP)

typedef __bf16 bf16x8 __attribute__((ext_vector_type(8)));
typedef float  f32x4  __attribute__((ext_vector_type(4)));

__device__ __forceinline__ float sigmoidf_(float x) {
    return 1.0f / (1.0f + __expf(-x));
}
__device__ __forceinline__ float tanhf_(float x) {
    x = fminf(fmaxf(x, -15.0f), 15.0f);
    float e = __expf(2.0f * x);
    return (e - 1.0f) / (e + 1.0f);
}

// heavy (placement-agnostic) grid/group barrier: release add, relaxed poll,
// one acquire fence after passing.
__device__ __forceinline__ void sync_heavy(int* cnt, int target) {
    __syncthreads();                       // drains vmcnt/lgkmcnt
    if (threadIdx.x == 0) {
        __hip_atomic_fetch_add(cnt, 1, __ATOMIC_RELEASE, __HIP_MEMORY_SCOPE_AGENT);
        while (__hip_atomic_load(cnt, __ATOMIC_RELAXED, __HIP_MEMORY_SCOPE_AGENT) < target)
            __builtin_amdgcn_s_sleep(1);
    }
    __syncthreads();
    __builtin_amdgcn_fence(__ATOMIC_ACQUIRE, "agent");
}

// ---------------------------------------------------------------------------
// Fused weight pack: all f32 weights -> bf16 MFMA fragment order Bp[kc][n][8]
// ---------------------------------------------------------------------------
#define PK_B0   81920           // 64*1280   [Wl;Wr]
#define PK_B1   20480           // 40*512    Wp (300->320)
#define PK_B2   65536           // 64*1024   W0
#define PK_B3  131072           // 128*1024  W1
__global__ __launch_bounds__(256)
void pack_all_kernel(const float* __restrict__ Wl, const float* __restrict__ Wr,
                     const float* __restrict__ Wp, const float* __restrict__ W0,
                     const float* __restrict__ W1,
                     __hip_bfloat16* __restrict__ Bp,
                     __hip_bfloat16* __restrict__ BpWp,
                     __hip_bfloat16* __restrict__ BpW0,
                     __hip_bfloat16* __restrict__ BpW1)
{
    int gid = blockIdx.x * 256 + threadIdx.x;
    __hip_bfloat16 tmp[8];
    if (gid < PK_B0) {
        int kc = gid / NGATES, n = gid - kc * NGATES;
#pragma unroll
        for (int j = 0; j < 8; ++j) {
            int k = kc * 8 + j;
            float v = (k < HIDN) ? Wl[k * NGATES + n] : Wr[(k - HIDN) * NGATES + n];
            tmp[j] = __float2bfloat16(v);
        }
        *(bf16x8*)(Bp + (size_t)gid * 8) = *(const bf16x8*)tmp;
    } else if (gid < PK_B0 + PK_B1) {
        int u = gid - PK_B0;
        int kc = u >> 9, n = u & 511;
#pragma unroll
        for (int j = 0; j < 8; ++j) {
            int k = kc * 8 + j;
            tmp[j] = __float2bfloat16((k < WDIM) ? Wp[(size_t)k * MDIM + n] : 0.f);
        }
        *(bf16x8*)(BpWp + (size_t)u * 8) = *(const bf16x8*)tmp;
    } else if (gid < PK_B0 + PK_B1 + PK_B2) {
        int u = gid - PK_B0 - PK_B1;
        int kc = u >> 10, n = u & 1023;
#pragma unroll
        for (int j = 0; j < 8; ++j)
            tmp[j] = __float2bfloat16(W0[(size_t)(kc * 8 + j) * MLPD + n]);
        *(bf16x8*)(BpW0 + (size_t)u * 8) = *(const bf16x8*)tmp;
    } else if (gid < PK_B0 + PK_B1 + PK_B2 + PK_B3) {
        int u = gid - PK_B0 - PK_B1 - PK_B2;
        int kc = u >> 10, n = u & 1023;
#pragma unroll
        for (int j = 0; j < 8; ++j)
            tmp[j] = __float2bfloat16(W1[(size_t)(kc * 8 + j) * MLPD + n]);
        *(bf16x8*)(BpW1 + (size_t)u * 8) = *(const bf16x8*)tmp;
    }
}

// ---------------------------------------------------------------------------
// State layout (group-major): row(b, s) = (b>>3)*512 + s*8 + (b&7); [row][256]
// ---------------------------------------------------------------------------
__device__ __forceinline__ size_t grow(int b, int s) {
    return ((size_t)(b >> 3) << 9) + ((size_t)s << 3) + (b & 7);
}

// ---------------------------------------------------------------------------
// K1: embed gather + projection via MFMA (writes group layout).
// ---------------------------------------------------------------------------
__global__ __launch_bounds__(256)
void embed_mfma_kernel(const int* __restrict__ sent,
                       const float* __restrict__ emb,
                       const __hip_bfloat16* __restrict__ BpWp,  // [40][512][8]
                       const float* __restrict__ bp,
                       __hip_bfloat16* __restrict__ hout,
                       float* __restrict__ cout)
{
    __shared__ __align__(16) __hip_bfloat16 Ae[WDIMP / 8][32][8];   // 20 KB
    const int tid  = threadIdx.x;
    const int tok0 = blockIdx.x * 32;

#pragma unroll
    for (int i = 0; i < 20; ++i) {
        int idx = i * 256 + tid;              // over 32 rows x 160 k-pairs
        int r  = idx / 160;
        int kp = idx - r * 160;
        int k  = kp * 2;
        float2 v = make_float2(0.f, 0.f);
        if (k < WDIM)
            v = *(const float2*)&emb[(size_t)sent[tok0 + r] * WDIM + k];
        __hip_bfloat162 h2;
        h2.x = __float2bfloat16(v.x);
        h2.y = __float2bfloat16(v.y);
        *(__hip_bfloat162*)&Ae[k >> 3][r][k & 7] = h2;
    }
    __syncthreads();

    const int lane = tid & 63;
    const int wid  = tid >> 6;
    const int l15  = lane & 15;
    const int kgrp = lane >> 4;
    const int col0 = blockIdx.y * 256 + wid * 64;

    f32x4 acc[2][4];
#pragma unroll
    for (int rf = 0; rf < 2; ++rf)
#pragma unroll
        for (int cf = 0; cf < 4; ++cf)
            acc[rf][cf] = (f32x4){0.f, 0.f, 0.f, 0.f};

    const bf16x8* BpV = (const bf16x8*)BpWp;
#pragma unroll
    for (int ks = 0; ks < WDIMP / 32; ++ks) {
        const int kc = ks * 4 + kgrp;
        bf16x8 a0 = *(const bf16x8*)&Ae[kc][l15][0];
        bf16x8 a1 = *(const bf16x8*)&Ae[kc][16 + l15][0];
        const bf16x8* Brow = BpV + (size_t)kc * MDIM + col0 + l15;
#pragma unroll
        for (int cf = 0; cf < 4; ++cf) {
            bf16x8 bfr = Brow[cf * 16];
            acc[0][cf] = __builtin_amdgcn_mfma_f32_16x16x32_bf16(a0, bfr, acc[0][cf], 0, 0, 0);
            acc[1][cf] = __builtin_amdgcn_mfma_f32_16x16x32_bf16(a1, bfr, acc[1][cf], 0, 0, 0);
        }
    }

#pragma unroll
    for (int rf = 0; rf < 2; ++rf)
#pragma unroll
        for (int reg = 0; reg < 4; ++reg) {
            int row = tok0 + rf * 16 + kgrp * 4 + reg;   // token = b*64+s
            int b = row >> 6, s = row & 63;
            size_t sr = grow(b, s);
#pragma unroll
            for (int cf = 0; cf < 4; ++cf) {
                int col = col0 + cf * 16 + l15;
                float v = acc[rf][cf][reg] + bp[col];
                if (col < HIDN)
                    hout[sr * HIDN + col] = __float2bfloat16(v);
                else
                    cout[sr * HIDN + (col - HIDN)] = v;
            }
        }
}

// ---------------------------------------------------------------------------
// K2: PERSISTENT tree kernel — all 63 levels, cooperative launch.
// 256 blocks x 512 threads. grp = (bx&7)*2 + (bx>>7); slice = (bx>>3)&15.
// B-slice (80 KB) staged once in LDS; c-state (slice-local, block-local)
// lives in LDS (f32, double-buffered, padded). Per level: MFMA GEMM on h
// (global, ping-pong) + in-register LSTM cell. Group barrier per level:
// FAST (all 16 slice-blocks of every group verified same-XCD via
// HW_REG_XCC_ID): relaxed agent atomics + buffer_inv sc0 (L1-only inval;
// h stores are write-through to the shared XCD L2).
// HEAVY fallback: release/acquire agent fences (always correct).
// ---------------------------------------------------------------------------
__global__ __launch_bounds__(512, 2)
void tree_persistent(__hip_bfloat16* __restrict__ h0g, float* __restrict__ c0g,
                     __hip_bfloat16* __restrict__ h1g, float* __restrict__ c1g,
                     const __hip_bfloat16* __restrict__ Bp,
                     const float* __restrict__ bc,
                     int* __restrict__ bar)
{
    __shared__ __align__(16) __hip_bfloat16 Bs[64][5][16][8];   // 80 KB
    __shared__ __align__(16) float cs[2][512][17];              // 69.6 KB, padded
    __shared__ int sflag;

    const int tid  = threadIdx.x;
    const int lane = tid & 63;
    const int wid  = tid >> 6;          // 0..7
    const int l15  = lane & 15;
    const int kgrp = lane >> 4;

    const int bx    = blockIdx.x;
    const int grp   = (bx & 7) * 2 + ((bx >> 3) >> 4);
    const int slice = (bx >> 3) & 15;
    const size_t goff = (size_t)grp * 512 * HIDN;

    // ---- stage B-slice once: 10 x (512 thr x 16 B) = 80 KB
#pragma unroll
    for (int i = 0; i < 10; ++i) {
        int flat = i * 512 + tid;              // (kc*5+g)*16 + j
        int kc  = flat / 80;
        int rem = flat - kc * 80;
        int g   = rem >> 4;
        int j   = rem & 15;
        const __hip_bfloat16* src =
            Bp + ((size_t)kc * NGATES + g * HIDN + slice * 16 + j) * 8;
        __builtin_amdgcn_global_load_lds(
            (const __attribute__((address_space(1))) unsigned int*)src,
            (__attribute__((address_space(3))) unsigned int*)
                ((char*)&Bs[0][0][0][0] + (size_t)flat * 16),
            16, 0, 0);
    }

    // ---- stage initial c-state into LDS buf 0 (512 rows x 16 cols)
#pragma unroll
    for (int i = 0; i < 4; ++i) {
        int idx = i * 512 + tid;               // 2048 float4s
        int r = idx >> 2, q = idx & 3;
        float4 v = *(const float4*)&c0g[goff + (size_t)r * HIDN + slice * 16 + q * 4];
        *(float4*)&cs[0][r][q * 4] = v;
    }

    // ---- XCD placement check -> pick barrier flavor (correct either way)
    int xcd = 0;
    asm volatile("s_getreg_b32 %0, hwreg(HW_REG_XCC_ID)" : "=s"(xcd));
    if (tid == 0 && slice == 0)
        __hip_atomic_store(&bar[BAR_XCD + grp], xcd, __ATOMIC_RELAXED, __HIP_MEMORY_SCOPE_AGENT);
    sync_heavy(&bar[BAR_G0], 256);
    if (tid == 0) {
        int lead = __hip_atomic_load(&bar[BAR_XCD + grp], __ATOMIC_RELAXED, __HIP_MEMORY_SCOPE_AGENT);
        if (lead != xcd)
            __hip_atomic_fetch_add(&bar[BAR_BAD], 1, __ATOMIC_RELAXED, __HIP_MEMORY_SCOPE_AGENT);
    }
    sync_heavy(&bar[BAR_G1], 256);
    if (tid == 0)
        sflag = (__hip_atomic_load(&bar[BAR_BAD], __ATOMIC_RELAXED, __HIP_MEMORY_SCOPE_AGENT) == 0);
    __syncthreads();
    const bool fast = (sflag != 0);

    const int col = slice * 16 + l15;
    float bias[5];
#pragma unroll
    for (int g = 0; g < 5; ++g) bias[g] = bc[g * HIDN + col];

    __hip_bfloat16* hA = h0g + goff;
    __hip_bfloat16* hB = h1g + goff;

    int cur = 0;
#pragma unroll 1
    for (int t = 1; t < SEQN; ++t) {
        const int R = SEQN - t;
        const __hip_bfloat16* hin = (t & 1) ? hA : hB;
        __hip_bfloat16*      hout = (t & 1) ? hB : hA;

        const int nfrag = (8 * R + 15) >> 4;
        const int nf = (nfrag - wid + 7) >> 3;   // my frag count (0..4)

        if (nf > 0) {
            f32x4 acc[4][5];
#pragma unroll
            for (int i = 0; i < 4; ++i)
#pragma unroll
                for (int g = 0; g < 5; ++g)
                    acc[i][g] = (f32x4){0.f, 0.f, 0.f, 0.f};

            const __hip_bfloat16* aptr[4];
#pragma unroll
            for (int i = 0; i < 4; ++i)
                aptr[i] = hin + (size_t)((wid + 8 * i) * 16 + l15) * HIDN;

#pragma unroll 1
            for (int ks = 0; ks < 16; ++ks) {
                const int kg   = ks * 32 + kgrp * 8;
                const int half = kg >> 8;          // 0=left, 1=right(+8 rows)
                const int kl   = kg & 255;
                bf16x8 bb[5];
#pragma unroll
                for (int g = 0; g < 5; ++g)
                    bb[g] = *(const bf16x8*)&Bs[ks * 4 + kgrp][g][l15][0];
#pragma unroll
                for (int i = 0; i < 4; ++i) {
                    if (i < nf) {
                        bf16x8 a = *(const bf16x8*)(aptr[i] + half * (8 * HIDN) + kl);
#pragma unroll
                        for (int g = 0; g < 5; ++g)
                            acc[i][g] = __builtin_amdgcn_mfma_f32_16x16x32_bf16(a, bb[g], acc[i][g], 0, 0, 0);
                    }
                }
            }

            // epilogue: C row = (lane>>4)*4+reg, C col = l15
#pragma unroll
            for (int i = 0; i < 4; ++i) {
                if (i < nf) {
                    const int f = wid + 8 * i;
#pragma unroll
                    for (int reg = 0; reg < 4; ++reg) {
                        int r = f * 16 + kgrp * 4 + reg;
                        int p = r >> 3;
                        if (p < R) {
                            float clv = cs[cur][r][l15];
                            float crv = cs[cur][r + 8][l15];
                            float i_ = acc[i][0][reg] + bias[0];
                            float fl = acc[i][1][reg] + bias[1];
                            float fr = acc[i][2][reg] + bias[2];
                            float o_ = acc[i][3][reg] + bias[3];
                            float g_ = acc[i][4][reg] + bias[4];
                            float c  = clv * sigmoidf_(fl) + crv * sigmoidf_(fr)
                                     + sigmoidf_(i_) * tanhf_(g_);
                            hout[(size_t)r * HIDN + col] = __float2bfloat16(sigmoidf_(o_) * tanhf_(c));
                            cs[cur ^ 1][r][l15] = c;
                        }
                    }
                }
            }
        }

        // ---- per-level group barrier (16 slice-blocks of this group)
        __syncthreads();   // drains vmcnt (h stores -> L2) + LDS writes
        {
            int* cnt = &bar[BAR_LVL + (t - 1) * NGRP + grp];
            if (fast) {
                if (tid == 0) {
                    __hip_atomic_fetch_add(cnt, 1, __ATOMIC_RELAXED, __HIP_MEMORY_SCOPE_AGENT);
                    while (__hip_atomic_load(cnt, __ATOMIC_RELAXED, __HIP_MEMORY_SCOPE_AGENT) < NSLICE)
                        __builtin_amdgcn_s_sleep(1);
                }
                __syncthreads();
                asm volatile("buffer_inv sc0" ::: "memory");   // L1-only invalidate
            } else {
                if (tid == 0) {
                    __hip_atomic_fetch_add(cnt, 1, __ATOMIC_RELEASE, __HIP_MEMORY_SCOPE_AGENT);
                    while (__hip_atomic_load(cnt, __ATOMIC_RELAXED, __HIP_MEMORY_SCOPE_AGENT) < NSLICE)
                        __builtin_amdgcn_s_sleep(1);
                }
                __syncthreads();
                __builtin_amdgcn_fence(__ATOMIC_ACQUIRE, "agent");
            }
        }
        cur ^= 1;
    }

    // ---- export root c (pos 0, rows 0..7) for the MLP head
    if (tid < 128) {
        int r = tid >> 4, j = tid & 15;
        c1g[goff + (size_t)r * HIDN + slice * 16 + j] = cs[cur][r][j];
    }
}

// ---------------------------------------------------------------------------
// Assemble MLP input (bf16): x[b,:] = [ h(root_b) | bf16(c(root_b)) ]
// ---------------------------------------------------------------------------
__global__ __launch_bounds__(256)
void gather_root_kernel(const __hip_bfloat16* __restrict__ h,
                        const float* __restrict__ c,
                        __hip_bfloat16* __restrict__ x)
{
    int idx = blockIdx.x * 256 + threadIdx.x;     // 128*512
    int b   = idx >> 9;
    int col = idx & 511;
    size_t sr = grow(b, 0);                       // root = pos 0
    __hip_bfloat16 v = (col < HIDN) ? h[sr * HIDN + col]
                                    : __float2bfloat16(c[sr * HIDN + (col - HIDN)]);
    x[idx] = v;
}

// ---------------------------------------------------------------------------
// K3: MFMA dense layer  out[128, N] = relu(A[128, K] @ W + bias), bf16 I/O.
// ---------------------------------------------------------------------------
template <int K, int N, bool RELU>
__global__ __launch_bounds__(256)
void mlp_mfma_kernel(const __hip_bfloat16* __restrict__ A,
                     const __hip_bfloat16* __restrict__ Bp,
                     const float* __restrict__ bias,
                     __hip_bfloat16* __restrict__ out)
{
    const int lane = threadIdx.x & 63;
    const int wid  = threadIdx.x >> 6;
    const int l15  = lane & 15;
    const int kgrp = lane >> 4;
    const int m0   = blockIdx.x * 32;
    const int col0 = blockIdx.y * 64 + wid * 16;

    f32x4 acc[2];
    acc[0] = (f32x4){0.f, 0.f, 0.f, 0.f};
    acc[1] = (f32x4){0.f, 0.f, 0.f, 0.f};

    const bf16x8* BpV = (const bf16x8*)Bp;
#pragma unroll 4
    for (int ks = 0; ks < K / 32; ++ks) {
        const int kl = ks * 32 + kgrp * 8;
        bf16x8 a0 = *(const bf16x8*)(A + (size_t)(m0 + l15)      * K + kl);
        bf16x8 a1 = *(const bf16x8*)(A + (size_t)(m0 + 16 + l15) * K + kl);
        bf16x8 bfr = BpV[(size_t)(ks * 4 + kgrp) * N + col0 + l15];
        acc[0] = __builtin_amdgcn_mfma_f32_16x16x32_bf16(a0, bfr, acc[0], 0, 0, 0);
        acc[1] = __builtin_amdgcn_mfma_f32_16x16x32_bf16(a1, bfr, acc[1], 0, 0, 0);
    }

    const int col = col0 + l15;
    const float bv = bias[col];
#pragma unroll
    for (int rf = 0; rf < 2; ++rf)
#pragma unroll
        for (int reg = 0; reg < 4; ++reg) {
            int m = m0 + rf * 16 + kgrp * 4 + reg;
            float v = acc[rf][reg] + bv;
            if (RELU) v = fmaxf(v, 0.f);
            out[(size_t)m * N + col] = __float2bfloat16(v);
        }
}

// ---------------------------------------------------------------------------
// K4: final layer (N=3): one wave per row, lane-parallel K, shuffle reduce.
// ---------------------------------------------------------------------------
__global__ __launch_bounds__(256)
void mlp_out_kernel(const __hip_bfloat16* __restrict__ A,
                    const float* __restrict__ Wo,
                    const float* __restrict__ bo,
                    float* __restrict__ out)
{
    const int lane = threadIdx.x & 63;
    const int row  = blockIdx.x * 4 + (threadIdx.x >> 6);
    float a0 = 0.f, a1 = 0.f, a2 = 0.f;
    for (int k = lane; k < MLPD; k += 64) {
        float x = __bfloat162float(A[(size_t)row * MLPD + k]);
        a0 += x * Wo[k * NCLS + 0];
        a1 += x * Wo[k * NCLS + 1];
        a2 += x * Wo[k * NCLS + 2];
    }
#pragma unroll
    for (int off = 32; off >= 1; off >>= 1) {
        a0 += __shfl_down(a0, off, 64);
        a1 += __shfl_down(a1, off, 64);
        a2 += __shfl_down(a2, off, 64);
    }
    if (lane == 0) {
        out[row * NCLS + 0] = a0 + bo[0];
        out[row * NCLS + 1] = a1 + bo[1];
        out[row * NCLS + 2] = a2 + bo[2];
    }
}

// ---------------------------------------------------------------------------
extern "C" void kernel_launch(void* const* d_in, const int* in_sizes, int n_in,
                              void* d_out, int out_size, void* d_ws, size_t ws_size,
                              hipStream_t stream)
{
    const int*   sent = (const int*)d_in[0];
    const float* emb  = (const float*)d_in[2];
    const float* Wp   = (const float*)d_in[3];
    const float* bp   = (const float*)d_in[4];
    const float* Wl   = (const float*)d_in[5];
    const float* Wr   = (const float*)d_in[6];
    const float* bc   = (const float*)d_in[7];
    const float* W0   = (const float*)d_in[8];
    const float* b0   = (const float*)d_in[9];
    const float* W1   = (const float*)d_in[10];
    const float* b1   = (const float*)d_in[11];
    const float* Wo   = (const float*)d_in[12];
    const float* bo   = (const float*)d_in[13];
    float* outp = (float*)d_out;

    const size_t NSTATE = (size_t)BATCHN * SEQN * HIDN;

    char* p = (char*)d_ws;
    __hip_bfloat16* h0   = (__hip_bfloat16*)p;  p += NSTATE * 2;
    __hip_bfloat16* h1   = (__hip_bfloat16*)p;  p += NSTATE * 2;
    float* c0            = (float*)p;           p += NSTATE * 4;
    float* c1            = (float*)p;           p += NSTATE * 4;
    __hip_bfloat16* Bp   = (__hip_bfloat16*)p;  p += (size_t)512 * NGATES * 2;
    __hip_bfloat16* BpWp = (__hip_bfloat16*)p;  p += (size_t)WDIMP * MDIM * 2;
    __hip_bfloat16* BpW0 = (__hip_bfloat16*)p;  p += (size_t)MDIM * MLPD * 2;
    __hip_bfloat16* BpW1 = (__hip_bfloat16*)p;  p += (size_t)MLPD * MLPD * 2;
    __hip_bfloat16* xr   = (__hip_bfloat16*)p;  p += (size_t)BATCHN * MDIM * 2;
    __hip_bfloat16* x0   = (__hip_bfloat16*)p;  p += (size_t)BATCHN * MLPD * 2;
    __hip_bfloat16* x1   = (__hip_bfloat16*)p;  p += (size_t)BATCHN * MLPD * 2;
    int* bar             = (int*)p;             p += (size_t)BAR_TOT * 4;

    // 0) zero barrier words + pack weights
    hipMemsetAsync(bar, 0, (size_t)BAR_TOT * 4, stream);
    const int PK_TOT = PK_B0 + PK_B1 + PK_B2 + PK_B3;
    pack_all_kernel<<<(PK_TOT + 255) / 256, 256, 0, stream>>>(
        Wl, Wr, Wp, W0, W1, Bp, BpWp, BpW0, BpW1);

    // 1) embedding gather + projection (MFMA, group-layout output)
    embed_mfma_kernel<<<dim3(BATCHN * SEQN / 32, 2), 256, 0, stream>>>(
        sent, emb, BpWp, bp, h0, c0);

    // 2) all 63 tree-LSTM levels in ONE cooperative persistent kernel
    {
        __hip_bfloat16* a0_ = h0; float* a1_ = c0;
        __hip_bfloat16* a2_ = h1; float* a3_ = c1;
        const __hip_bfloat16* a4_ = Bp;
        const float* a5_ = bc;
        int* a6_ = bar;
        void* kargs[] = {&a0_, &a1_, &a2_, &a3_, &a4_, &a5_, &a6_};
        hipLaunchCooperativeKernel((const void*)tree_persistent,
                                   dim3(256), dim3(512), kargs, 0, stream);
    }

    // 3) MLP head on root states (final h in h1; root c exported to c1)
    gather_root_kernel<<<(BATCHN * MDIM) / 256, 256, 0, stream>>>(h1, c1, xr);
    mlp_mfma_kernel<MDIM, MLPD, true><<<dim3(4, 16), 256, 0, stream>>>(xr, BpW0, b0, x0);
    mlp_mfma_kernel<MLPD, MLPD, true><<<dim3(4, 16), 256, 0, stream>>>(x0, BpW1, b1, x1);
    mlp_out_kernel<<<32, 256, 0, stream>>>(x1, Wo, bo, outp);
}